// Round 2
// baseline (1047.849 us; speedup 1.0000x reference)
//
#include <hip/hip_runtime.h>
#include <math.h>

#define B_  32768
#define K_  1024
#define N_  2048

typedef __bf16 bf16x8 __attribute__((ext_vector_type(8)));
typedef float  f32x4  __attribute__((ext_vector_type(4)));
typedef float  f4     __attribute__((ext_vector_type(4)));
typedef unsigned short us4 __attribute__((ext_vector_type(4)));

__device__ __forceinline__ unsigned short f2bf(float f) {
    unsigned u = __float_as_uint(f);
    u += 0x7fffu + ((u >> 16) & 1u);   // round-to-nearest-even
    return (unsigned short)(u >> 16);
}
__device__ __forceinline__ float bf2f(unsigned short s) {
    return __uint_as_float(((unsigned)s) << 16);
}
__device__ __forceinline__ float sigm(float x) {
    return 1.f / (1.f + __expf(-x));                 // x->-inf: 1/inf = 0, safe
}
__device__ __forceinline__ float tanh_fast(float x) {
    return 1.f - 2.f / (__expf(2.f * x) + 1.f);      // +inf -> 1, -inf -> -1, safe
}

// ---------------- pack x || h -> XH bf16 [B, 1024] ----------------
__global__ __launch_bounds__(256) void cvt_xh_kernel(const float* __restrict__ x,
                                                     const float* __restrict__ h,
                                                     unsigned short* __restrict__ XH) {
    unsigned i = (blockIdx.x * 256u + threadIdx.x) * 4u;   // element index in XH
    unsigned col = i & 1023u;
    unsigned row = i >> 10;
    const float* src = (col < 512u) ? (x + (size_t)row * 512u + col)
                                    : (h + (size_t)row * 512u + (col - 512u));
    f4 v = *(const f4*)src;
    us4 o;
    o.x = f2bf(v.x); o.y = f2bf(v.y); o.z = f2bf(v.z); o.w = f2bf(v.w);
    *(us4*)(XH + i) = o;
}

// ---------------- transpose-pack weights -> Wt bf16 [N=2048, K=1024] ----------------
// Wt[n = g*512 + j][k]:  k<512 -> U_g[k][j],  k>=512 -> V_g[k-512][j]
__global__ __launch_bounds__(256) void cvt_w_kernel(
    const float* __restrict__ Uf, const float* __restrict__ Vf,
    const float* __restrict__ Ui, const float* __restrict__ Vi,
    const float* __restrict__ Uo, const float* __restrict__ Vo,
    const float* __restrict__ Uc, const float* __restrict__ Vc,
    unsigned short* __restrict__ Wt) {
    __shared__ float tile[64][65];
    const float* srcs[8] = {Uf, Vf, Ui, Vi, Uo, Vo, Uc, Vc};
    const int w   = blockIdx.z;           // 0..7 : Uf,Vf,Ui,Vi,Uo,Vo,Uc,Vc
    const float* src = srcs[w];
    const int g   = w >> 1;
    const int isV = w & 1;
    const int j0  = blockIdx.x * 64;
    const int k0  = blockIdx.y * 64;
    const int t   = threadIdx.x;
    const int ty  = t >> 6, tx = t & 63;
    #pragma unroll
    for (int r = 0; r < 16; ++r) {
        int kl = ty * 16 + r;
        tile[kl][tx] = src[(size_t)(k0 + kl) * 512 + j0 + tx];   // coalesced over j
    }
    __syncthreads();
    #pragma unroll
    for (int r = 0; r < 16; ++r) {
        int jl = ty * 16 + r;
        Wt[(size_t)(g * 512 + j0 + jl) * 1024 + isV * 512 + k0 + tx] = f2bf(tile[tx][jl]); // coalesced over k
    }
}

// ---------------- fused GEMM + LSTM gates ----------------
// 128x128 tile, BK=64, 4 waves, 16x16x32 MFMA, register staging with K+1 prefetch.
// Column layout trick: a block's 128 columns are {g*512 + jblk + 0..31, g=0..3}
// (4 gates x SAME 32 hidden units). Per wave, nt indexes the gate, so
// acc[mt][0..3][rr] holds f,i,o,c pre-activations for one (row, j) in-register.
// Epilogue applies sigmoid/tanh + cell update and writes h_new/c_new as f32 with
// 64B line-coalesced segments. Pre is never materialized.
__global__ __launch_bounds__(256, 2) void gemm_fused_kernel(
    const unsigned short* __restrict__ XH,
    const unsigned short* __restrict__ Wt,
    const float* __restrict__ cell,
    const float* __restrict__ bfp, const float* __restrict__ bip,
    const float* __restrict__ bop, const float* __restrict__ bcp,
    float* __restrict__ out) {
    __shared__ __attribute__((aligned(16))) unsigned short As[128 * 64];
    __shared__ __attribute__((aligned(16))) unsigned short Bs[128 * 64];
    const int t    = threadIdx.x;
    const int lane = t & 63;
    const int w    = t >> 6;
    const int wm   = w >> 1;
    const int wn   = w & 1;

    // XCD-aware swizzle (bijective: 4096 % 8 == 0). Round-robin dispatch ->
    // each XCD gets a contiguous chunk of m-strips with n fastest, so the
    // 16 n-blocks sharing one 256KB XH strip run on the same XCD's L2.
    const unsigned lin = blockIdx.y * gridDim.x + blockIdx.x;   // x fastest
    const unsigned wg  = (lin & 7u) * 512u + (lin >> 3);
    const int jblk = (int)(wg & 15u) * 32;     // hidden-unit block: j in [jblk, jblk+32)
    const int m0   = (int)(wg >> 4) * 128;

    f32x4 acc[4][4];
    #pragma unroll
    for (int i = 0; i < 4; ++i)
        #pragma unroll
        for (int j = 0; j < 4; ++j) { f32x4 z = {0.f, 0.f, 0.f, 0.f}; acc[i][j] = z; }

    // staging geometry: thread t stages slots L = s*256+t
    // LDS chunk layout (16B chunks): slot(r,c) = r*8 + (c ^ (r&7))
    // Bs local row r -> Wt row (r>>5)*512 + jblk + (r&31)   (gate-major 4x32)
    size_t aOff[4], bOff[4];
    int    lOff[4];
    #pragma unroll
    for (int s = 0; s < 4; ++s) {
        int L  = s * 256 + t;
        int r  = L >> 3;
        int gc = (L & 7) ^ (r & 7);
        aOff[s] = (size_t)r * K_ + gc * 8;
        int wrow = (r >> 5) * 512 + jblk + (r & 31);
        bOff[s] = (size_t)wrow * K_ + gc * 8;
        lOff[s] = L * 8;                     // slot L at byte L*16
    }
    const unsigned short* xb = XH + (size_t)m0 * K_;

    uint4 pa[4], pb[4];
    #pragma unroll
    for (int s = 0; s < 4; ++s) {
        pa[s] = *(const uint4*)(xb + aOff[s]);
        pb[s] = *(const uint4*)(Wt + bOff[s]);
    }

    for (int it = 0; it < K_ / 64; ++it) {
        __syncthreads();   // all waves done reading LDS from previous iteration
        #pragma unroll
        for (int s = 0; s < 4; ++s) {
            *(uint4*)(As + lOff[s]) = pa[s];
            *(uint4*)(Bs + lOff[s]) = pb[s];
        }
        __syncthreads();   // writes visible to all waves

        if (it + 1 < K_ / 64) {
            const int k1 = (it + 1) * 64;
            #pragma unroll
            for (int s = 0; s < 4; ++s) {
                pa[s] = *(const uint4*)(xb + aOff[s] + k1);   // in flight through MFMAs
                pb[s] = *(const uint4*)(Wt + bOff[s] + k1);
            }
        }

        #pragma unroll
        for (int ks = 0; ks < 2; ++ks) {
            bf16x8 af[4], bfr[4];
            const int c = ks * 4 + (lane >> 4);
            #pragma unroll
            for (int mt = 0; mt < 4; ++mt) {
                int r = wm * 64 + mt * 16 + (lane & 15);
                int slot = r * 8 + (c ^ (r & 7));
                af[mt] = *(const bf16x8*)(As + slot * 8);
            }
            #pragma unroll
            for (int nt = 0; nt < 4; ++nt) {
                int r = nt * 32 + wn * 16 + (lane & 15);    // nt = gate, 16 j's per wn
                int slot = r * 8 + (c ^ (r & 7));
                bfr[nt] = *(const bf16x8*)(Bs + slot * 8);
            }
            #pragma unroll
            for (int mt = 0; mt < 4; ++mt)
                #pragma unroll
                for (int nt = 0; nt < 4; ++nt)
                    acc[mt][nt] = __builtin_amdgcn_mfma_f32_16x16x32_bf16(af[mt], bfr[nt], acc[mt][nt], 0, 0, 0);
        }
    }

    // fused epilogue: C/D layout col = lane&15 (-> j), row = (lane>>4)*4 + rr
    const int q = lane & 15;
    const int j = jblk + wn * 16 + q;
    const float bF = bfp[j], bI = bip[j], bO = bop[j], bC = bcp[j];
    float* __restrict__ hout = out + 65536;
    float* __restrict__ cout = out + 65536 + 16777216;
    const int rb = m0 + wm * 64 + ((lane >> 4) << 2);
    #pragma unroll
    for (int mt = 0; mt < 4; ++mt) {
        #pragma unroll
        for (int rr = 0; rr < 4; ++rr) {
            const int row = rb + mt * 16 + rr;
            const float sf = sigm(acc[mt][0][rr] + bF);
            const float si = sigm(acc[mt][1][rr] + bI);
            const float so = sigm(acc[mt][2][rr] + bO);
            const float ch = tanh_fast(acc[mt][3][rr] + bC);
            const float cold = cell[(size_t)row * 512 + j];
            const float cn = sf * cold + si * ch;
            const float hn = so * tanh_fast(cn);
            hout[(size_t)row * 512 + j] = hn;   // 16 consecutive floats per 16-lane group
            cout[(size_t)row * 512 + j] = cn;
        }
    }
}

// ---------------- logits + softmax from h_new ----------------
__global__ __launch_bounds__(256) void logits_kernel(const float* __restrict__ h,
                                                     const float* __restrict__ Wout,
                                                     const float* __restrict__ bout,
                                                     float* __restrict__ out) {
    const int t    = threadIdx.x;
    const int lane = t & 63;
    const int wv   = t >> 6;
    const int row  = blockIdx.x * 4 + wv;
    const float* hr = h + (size_t)row * 512 + lane * 8;
    f4 a = *(const f4*)(hr);
    f4 b = *(const f4*)(hr + 4);
    const float* wo = Wout + lane * 16;
    float p0 = 0.f, p1 = 0.f;
    #pragma unroll
    for (int k = 0; k < 4; ++k) { p0 += a[k] * wo[2 * k];     p1 += a[k] * wo[2 * k + 1]; }
    #pragma unroll
    for (int k = 0; k < 4; ++k) { p0 += b[k] * wo[8 + 2 * k]; p1 += b[k] * wo[8 + 2 * k + 1]; }
    #pragma unroll
    for (int off = 32; off > 0; off >>= 1) {
        p0 += __shfl_down(p0, off);
        p1 += __shfl_down(p1, off);
    }
    if (lane == 0) {
        float l0 = p0 + bout[0], l1 = p1 + bout[1];
        float mx = fmaxf(l0, l1);
        float e0 = __expf(l0 - mx), e1 = __expf(l1 - mx);
        float s  = e0 + e1;
        out[(size_t)row * 2 + 0] = e0 / s;
        out[(size_t)row * 2 + 1] = e1 / s;
    }
}

// ---------------- fallback (only if workspace is too small): naive fp32 ----------------
__global__ __launch_bounds__(256) void fallback_kernel(
    const float* __restrict__ x, const float* __restrict__ h, const float* __restrict__ cell,
    const float* __restrict__ Uf, const float* __restrict__ Vf, const float* __restrict__ bfp,
    const float* __restrict__ Ui, const float* __restrict__ Vi, const float* __restrict__ bip,
    const float* __restrict__ Uo, const float* __restrict__ Vo, const float* __restrict__ bop,
    const float* __restrict__ Uc, const float* __restrict__ Vc, const float* __restrict__ bcp,
    const float* __restrict__ Wout, const float* __restrict__ bout, float* __restrict__ out) {
    const int row = blockIdx.x;
    const int t   = threadIdx.x;
    __shared__ float xs[512], hs[512];
    xs[t]       = x[(size_t)row * 512 + t];
    xs[t + 256] = x[(size_t)row * 512 + t + 256];
    hs[t]       = h[(size_t)row * 512 + t];
    hs[t + 256] = h[(size_t)row * 512 + t + 256];
    __syncthreads();
    float p0 = 0.f, p1 = 0.f;
    for (int jj = 0; jj < 2; ++jj) {
        const int j = t + jj * 256;
        float af = bfp[j], ai = bip[j], ao = bop[j], ac = bcp[j];
        for (int k = 0; k < 512; ++k) {
            float xv = xs[k], hv = hs[k];
            af += xv * Uf[k * 512 + j] + hv * Vf[k * 512 + j];
            ai += xv * Ui[k * 512 + j] + hv * Vi[k * 512 + j];
            ao += xv * Uo[k * 512 + j] + hv * Vo[k * 512 + j];
            ac += xv * Uc[k * 512 + j] + hv * Vc[k * 512 + j];
        }
        float gf = 1.f / (1.f + __expf(-af));
        float gi = 1.f / (1.f + __expf(-ai));
        float go = 1.f / (1.f + __expf(-ao));
        float ch = tanhf(ac);
        float cold = cell[(size_t)row * 512 + j];
        float cn = gf * cold + gi * ch;
        float hn = go * tanhf(cn);
        out[65536 + (size_t)row * 512 + j]            = hn;
        out[65536 + 16777216 + (size_t)row * 512 + j] = cn;
        p0 += hn * Wout[j * 2 + 0];
        p1 += hn * Wout[j * 2 + 1];
    }
    #pragma unroll
    for (int off = 32; off > 0; off >>= 1) {
        p0 += __shfl_down(p0, off);
        p1 += __shfl_down(p1, off);
    }
    __shared__ float r0[4], r1[4];
    if ((t & 63) == 0) { r0[t >> 6] = p0; r1[t >> 6] = p1; }
    __syncthreads();
    if (t == 0) {
        float l0 = r0[0] + r0[1] + r0[2] + r0[3] + bout[0];
        float l1 = r1[0] + r1[1] + r1[2] + r1[3] + bout[1];
        float mx = fmaxf(l0, l1);
        float e0 = __expf(l0 - mx), e1 = __expf(l1 - mx);
        float s  = e0 + e1;
        out[(size_t)row * 2 + 0] = e0 / s;
        out[(size_t)row * 2 + 1] = e1 / s;
    }
}

extern "C" void kernel_launch(void* const* d_in, const int* in_sizes, int n_in,
                              void* d_out, int out_size, void* d_ws, size_t ws_size,
                              hipStream_t stream) {
    const float* x    = (const float*)d_in[0];
    const float* h    = (const float*)d_in[1];
    const float* c    = (const float*)d_in[2];
    const float* Uf   = (const float*)d_in[3];
    const float* Vf   = (const float*)d_in[4];
    const float* bfp  = (const float*)d_in[5];
    const float* Ui   = (const float*)d_in[6];
    const float* Vi   = (const float*)d_in[7];
    const float* bip  = (const float*)d_in[8];
    const float* Uo   = (const float*)d_in[9];
    const float* Vo   = (const float*)d_in[10];
    const float* bop  = (const float*)d_in[11];
    const float* Uc   = (const float*)d_in[12];
    const float* Vc   = (const float*)d_in[13];
    const float* bcp  = (const float*)d_in[14];
    const float* Wout = (const float*)d_in[15];
    const float* bout = (const float*)d_in[16];
    float* out = (float*)d_out;

    const size_t needXH = (size_t)B_ * K_ * 2;   // 64 MB
    const size_t needWt = (size_t)N_ * K_ * 2;   //  4 MB

    if (ws_size >= needXH + needWt) {
        unsigned short* XH = (unsigned short*)d_ws;
        unsigned short* Wt = (unsigned short*)((char*)d_ws + needXH);

        cvt_xh_kernel<<<(B_ * K_) / (256 * 4), 256, 0, stream>>>(x, h, XH);
        cvt_w_kernel<<<dim3(8, 8, 8), 256, 0, stream>>>(Uf, Vf, Ui, Vi, Uo, Vo, Uc, Vc, Wt);
        gemm_fused_kernel<<<dim3(16, 256), 256, 0, stream>>>(XH, Wt, c, bfp, bip, bop, bcp, out);
        logits_kernel<<<B_ / 4, 256, 0, stream>>>(out + 65536, Wout, bout, out);
    } else {
        fallback_kernel<<<B_, 256, 0, stream>>>(x, h, c, Uf, Vf, bfp, Ui, Vi, bip,
                                                Uo, Vo, bop, Uc, Vc, bcp, Wout, bout, out);
    }
}

// Round 3
// 993.816 us; speedup vs baseline: 1.0544x; 1.0544x over previous
//
#include <hip/hip_runtime.h>
#include <math.h>

#define B_  32768
#define K_  1024
#define N_  2048

typedef __bf16 bf16x8 __attribute__((ext_vector_type(8)));
typedef float  f32x4  __attribute__((ext_vector_type(4)));
typedef float  f4     __attribute__((ext_vector_type(4)));
typedef unsigned short us4 __attribute__((ext_vector_type(4)));

__device__ __forceinline__ unsigned short f2bf(float f) {
    unsigned u = __float_as_uint(f);
    u += 0x7fffu + ((u >> 16) & 1u);   // round-to-nearest-even
    return (unsigned short)(u >> 16);
}
__device__ __forceinline__ float bf2f(unsigned short s) {
    return __uint_as_float(((unsigned)s) << 16);
}
__device__ __forceinline__ float sigm(float x) {
    return 1.f / (1.f + __expf(-x));                 // x->-inf: 1/inf = 0, safe
}
__device__ __forceinline__ float tanh_fast(float x) {
    return 1.f - 2.f / (__expf(2.f * x) + 1.f);      // +inf -> 1, -inf -> -1, safe
}

// ---------------- pack x || h -> XH bf16 [B, 1024] ----------------
__global__ __launch_bounds__(256) void cvt_xh_kernel(const float* __restrict__ x,
                                                     const float* __restrict__ h,
                                                     unsigned short* __restrict__ XH) {
    unsigned i = (blockIdx.x * 256u + threadIdx.x) * 4u;   // element index in XH
    unsigned col = i & 1023u;
    unsigned row = i >> 10;
    const float* src = (col < 512u) ? (x + (size_t)row * 512u + col)
                                    : (h + (size_t)row * 512u + (col - 512u));
    f4 v = *(const f4*)src;
    us4 o;
    o.x = f2bf(v.x); o.y = f2bf(v.y); o.z = f2bf(v.z); o.w = f2bf(v.w);
    *(us4*)(XH + i) = o;
}

// ---------------- transpose-pack weights -> Wt bf16 [N=2048, K=1024] ----------------
// Wt[n = g*512 + j][k]:  k<512 -> U_g[k][j],  k>=512 -> V_g[k-512][j]
__global__ __launch_bounds__(256) void cvt_w_kernel(
    const float* __restrict__ Uf, const float* __restrict__ Vf,
    const float* __restrict__ Ui, const float* __restrict__ Vi,
    const float* __restrict__ Uo, const float* __restrict__ Vo,
    const float* __restrict__ Uc, const float* __restrict__ Vc,
    unsigned short* __restrict__ Wt) {
    __shared__ float tile[64][65];
    const float* srcs[8] = {Uf, Vf, Ui, Vi, Uo, Vo, Uc, Vc};
    const int w   = blockIdx.z;           // 0..7 : Uf,Vf,Ui,Vi,Uo,Vo,Uc,Vc
    const float* src = srcs[w];
    const int g   = w >> 1;
    const int isV = w & 1;
    const int j0  = blockIdx.x * 64;
    const int k0  = blockIdx.y * 64;
    const int t   = threadIdx.x;
    const int ty  = t >> 6, tx = t & 63;
    #pragma unroll
    for (int r = 0; r < 16; ++r) {
        int kl = ty * 16 + r;
        tile[kl][tx] = src[(size_t)(k0 + kl) * 512 + j0 + tx];   // coalesced over j
    }
    __syncthreads();
    #pragma unroll
    for (int r = 0; r < 16; ++r) {
        int jl = ty * 16 + r;
        Wt[(size_t)(g * 512 + j0 + jl) * 1024 + isV * 512 + k0 + tx] = f2bf(tile[tx][jl]); // coalesced over k
    }
}

// ---------------- fused GEMM + LSTM gates ----------------
// 128x128 tile, BK=64, 4 waves, 16x16x32 MFMA, register staging with K+1 prefetch.
// Block's 128 columns = {g*512 + jblk + 0..31, g=0..3}: per wave, nt indexes the
// gate, so acc[mt][0..3][rr] holds f,i,o,c pre-activations for one (row, j).
// Natural dispatch order (no swizzle): x = jblk fastest, matching the layout
// that measured 558 MB fetch in the unfused kernel.
// Epilogue: gates+cell update in-register, then h/c tiles staged through LDS
// (As/Bs reused, dead after K-loop) and streamed out as FULL 128B lines:
// each wave-instruction writes 8 complete aligned cache lines.
__global__ __launch_bounds__(256, 2) void gemm_fused_kernel(
    const unsigned short* __restrict__ XH,
    const unsigned short* __restrict__ Wt,
    const float* __restrict__ cell,
    const float* __restrict__ bfp, const float* __restrict__ bip,
    const float* __restrict__ bop, const float* __restrict__ bcp,
    float* __restrict__ out) {
    __shared__ __attribute__((aligned(16))) unsigned char smem[32 * 1024];
    unsigned short* As = (unsigned short*)smem;                 // 16 KB
    unsigned short* Bs = (unsigned short*)(smem + 16 * 1024);   // 16 KB
    const int t    = threadIdx.x;
    const int lane = t & 63;
    const int w    = t >> 6;
    const int wm   = w >> 1;
    const int wn   = w & 1;

    const int jblk = blockIdx.x * 32;          // hidden-unit block: j in [jblk, jblk+32)
    const int m0   = blockIdx.y * 128;

    f32x4 acc[4][4];
    #pragma unroll
    for (int i = 0; i < 4; ++i)
        #pragma unroll
        for (int j = 0; j < 4; ++j) { f32x4 z = {0.f, 0.f, 0.f, 0.f}; acc[i][j] = z; }

    // staging geometry: thread t stages slots L = s*256+t
    // LDS chunk layout (16B chunks): slot(r,c) = r*8 + (c ^ (r&7))
    // Bs local row r -> Wt row (r>>5)*512 + jblk + (r&31)   (gate-major 4x32)
    size_t aOff[4], bOff[4];
    int    lOff[4];
    #pragma unroll
    for (int s = 0; s < 4; ++s) {
        int L  = s * 256 + t;
        int r  = L >> 3;
        int gc = (L & 7) ^ (r & 7);
        aOff[s] = (size_t)r * K_ + gc * 8;
        int wrow = (r >> 5) * 512 + jblk + (r & 31);
        bOff[s] = (size_t)wrow * K_ + gc * 8;
        lOff[s] = L * 8;                     // slot L at byte L*16
    }
    const unsigned short* xb = XH + (size_t)m0 * K_;

    uint4 pa[4], pb[4];
    #pragma unroll
    for (int s = 0; s < 4; ++s) {
        pa[s] = *(const uint4*)(xb + aOff[s]);
        pb[s] = *(const uint4*)(Wt + bOff[s]);
    }

    for (int it = 0; it < K_ / 64; ++it) {
        __syncthreads();   // all waves done reading LDS from previous iteration
        #pragma unroll
        for (int s = 0; s < 4; ++s) {
            *(uint4*)(As + lOff[s]) = pa[s];
            *(uint4*)(Bs + lOff[s]) = pb[s];
        }
        __syncthreads();   // writes visible to all waves

        if (it + 1 < K_ / 64) {
            const int k1 = (it + 1) * 64;
            #pragma unroll
            for (int s = 0; s < 4; ++s) {
                pa[s] = *(const uint4*)(xb + aOff[s] + k1);   // in flight through MFMAs
                pb[s] = *(const uint4*)(Wt + bOff[s] + k1);
            }
        }

        #pragma unroll
        for (int ks = 0; ks < 2; ++ks) {
            bf16x8 af[4], bfr[4];
            const int c = ks * 4 + (lane >> 4);
            #pragma unroll
            for (int mt = 0; mt < 4; ++mt) {
                int r = wm * 64 + mt * 16 + (lane & 15);
                int slot = r * 8 + (c ^ (r & 7));
                af[mt] = *(const bf16x8*)(As + slot * 8);
            }
            #pragma unroll
            for (int nt = 0; nt < 4; ++nt) {
                int r = nt * 32 + wn * 16 + (lane & 15);    // nt = gate, 16 j's per wn
                int slot = r * 8 + (c ^ (r & 7));
                bfr[nt] = *(const bf16x8*)(Bs + slot * 8);
            }
            #pragma unroll
            for (int mt = 0; mt < 4; ++mt)
                #pragma unroll
                for (int nt = 0; nt < 4; ++nt)
                    acc[mt][nt] = __builtin_amdgcn_mfma_f32_16x16x32_bf16(af[mt], bfr[nt], acc[mt][nt], 0, 0, 0);
        }
    }

    // ---- fused epilogue ----
    // C/D layout: col = lane&15 (-> local j), row = (lane>>4)*4 + rr
    const int q   = lane & 15;
    const int jc  = wn * 16 + q;               // local col in [0,32)
    const int j   = jblk + jc;                 // global hidden idx
    const float bF = bfp[j], bI = bip[j], bO = bop[j], bC = bcp[j];
    const int rlb = wm * 64 + ((lane >> 4) << 2);   // local row base
    float hnv[16], cnv[16];
    #pragma unroll
    for (int mt = 0; mt < 4; ++mt) {
        #pragma unroll
        for (int rr = 0; rr < 4; ++rr) {
            const int rl  = rlb + mt * 16 + rr;
            const int row = m0 + rl;
            const float sf = sigm(acc[mt][0][rr] + bF);
            const float si = sigm(acc[mt][1][rr] + bI);
            const float so = sigm(acc[mt][2][rr] + bO);
            const float ch = tanh_fast(acc[mt][3][rr] + bC);
            const float cold = cell[(size_t)row * 512 + j];
            const float cn = sf * cold + si * ch;
            cnv[mt * 4 + rr] = cn;
            hnv[mt * 4 + rr] = so * tanh_fast(cn);
        }
    }

    // reuse As/Bs as a 128 x 36-padded f32 tile (18.4 KB); pad 36 keeps every
    // row 16B-aligned for ds_read_b128 and spreads banks across row groups.
    float* eb   = (float*)smem;
    float* hout = out + 65536;
    float* cout = out + 65536 + 16777216;

    __syncthreads();     // everyone done reading As/Bs for MFMA
    #pragma unroll
    for (int mt = 0; mt < 4; ++mt)
        #pragma unroll
        for (int rr = 0; rr < 4; ++rr)
            eb[(rlb + mt * 16 + rr) * 36 + jc] = hnv[mt * 4 + rr];
    __syncthreads();
    #pragma unroll
    for (int i = 0; i < 4; ++i) {   // each wave-instr: 64 lanes x 16B = 8 full 128B lines
        const int r  = i * 32 + (t >> 3);
        const int c4 = (t & 7) * 4;
        f4 v = *(const f4*)(eb + r * 36 + c4);
        *(f4*)(hout + (size_t)(m0 + r) * 512 + jblk + c4) = v;
    }
    __syncthreads();
    #pragma unroll
    for (int mt = 0; mt < 4; ++mt)
        #pragma unroll
        for (int rr = 0; rr < 4; ++rr)
            eb[(rlb + mt * 16 + rr) * 36 + jc] = cnv[mt * 4 + rr];
    __syncthreads();
    #pragma unroll
    for (int i = 0; i < 4; ++i) {
        const int r  = i * 32 + (t >> 3);
        const int c4 = (t & 7) * 4;
        f4 v = *(const f4*)(eb + r * 36 + c4);
        *(f4*)(cout + (size_t)(m0 + r) * 512 + jblk + c4) = v;
    }
}

// ---------------- logits + softmax from h_new ----------------
__global__ __launch_bounds__(256) void logits_kernel(const float* __restrict__ h,
                                                     const float* __restrict__ Wout,
                                                     const float* __restrict__ bout,
                                                     float* __restrict__ out) {
    const int t    = threadIdx.x;
    const int lane = t & 63;
    const int wv   = t >> 6;
    const int row  = blockIdx.x * 4 + wv;
    const float* hr = h + (size_t)row * 512 + lane * 8;
    f4 a = *(const f4*)(hr);
    f4 b = *(const f4*)(hr + 4);
    const float* wo = Wout + lane * 16;
    float p0 = 0.f, p1 = 0.f;
    #pragma unroll
    for (int k = 0; k < 4; ++k) { p0 += a[k] * wo[2 * k];     p1 += a[k] * wo[2 * k + 1]; }
    #pragma unroll
    for (int k = 0; k < 4; ++k) { p0 += b[k] * wo[8 + 2 * k]; p1 += b[k] * wo[8 + 2 * k + 1]; }
    #pragma unroll
    for (int off = 32; off > 0; off >>= 1) {
        p0 += __shfl_down(p0, off);
        p1 += __shfl_down(p1, off);
    }
    if (lane == 0) {
        float l0 = p0 + bout[0], l1 = p1 + bout[1];
        float mx = fmaxf(l0, l1);
        float e0 = __expf(l0 - mx), e1 = __expf(l1 - mx);
        float s  = e0 + e1;
        out[(size_t)row * 2 + 0] = e0 / s;
        out[(size_t)row * 2 + 1] = e1 / s;
    }
}

// ---------------- fallback (only if workspace is too small): naive fp32 ----------------
__global__ __launch_bounds__(256) void fallback_kernel(
    const float* __restrict__ x, const float* __restrict__ h, const float* __restrict__ cell,
    const float* __restrict__ Uf, const float* __restrict__ Vf, const float* __restrict__ bfp,
    const float* __restrict__ Ui, const float* __restrict__ Vi, const float* __restrict__ bip,
    const float* __restrict__ Uo, const float* __restrict__ Vo, const float* __restrict__ bop,
    const float* __restrict__ Uc, const float* __restrict__ Vc, const float* __restrict__ bcp,
    const float* __restrict__ Wout, const float* __restrict__ bout, float* __restrict__ out) {
    const int row = blockIdx.x;
    const int t   = threadIdx.x;
    __shared__ float xs[512], hs[512];
    xs[t]       = x[(size_t)row * 512 + t];
    xs[t + 256] = x[(size_t)row * 512 + t + 256];
    hs[t]       = h[(size_t)row * 512 + t];
    hs[t + 256] = h[(size_t)row * 512 + t + 256];
    __syncthreads();
    float p0 = 0.f, p1 = 0.f;
    for (int jj = 0; jj < 2; ++jj) {
        const int j = t + jj * 256;
        float af = bfp[j], ai = bip[j], ao = bop[j], ac = bcp[j];
        for (int k = 0; k < 512; ++k) {
            float xv = xs[k], hv = hs[k];
            af += xv * Uf[k * 512 + j] + hv * Vf[k * 512 + j];
            ai += xv * Ui[k * 512 + j] + hv * Vi[k * 512 + j];
            ao += xv * Uo[k * 512 + j] + hv * Vo[k * 512 + j];
            ac += xv * Uc[k * 512 + j] + hv * Vc[k * 512 + j];
        }
        float gf = 1.f / (1.f + __expf(-af));
        float gi = 1.f / (1.f + __expf(-ai));
        float go = 1.f / (1.f + __expf(-ao));
        float ch = tanhf(ac);
        float cold = cell[(size_t)row * 512 + j];
        float cn = gf * cold + gi * ch;
        float hn = go * tanhf(cn);
        out[65536 + (size_t)row * 512 + j]            = hn;
        out[65536 + 16777216 + (size_t)row * 512 + j] = cn;
        p0 += hn * Wout[j * 2 + 0];
        p1 += hn * Wout[j * 2 + 1];
    }
    #pragma unroll
    for (int off = 32; off > 0; off >>= 1) {
        p0 += __shfl_down(p0, off);
        p1 += __shfl_down(p1, off);
    }
    __shared__ float r0[4], r1[4];
    if ((t & 63) == 0) { r0[t >> 6] = p0; r1[t >> 6] = p1; }
    __syncthreads();
    if (t == 0) {
        float l0 = r0[0] + r0[1] + r0[2] + r0[3] + bout[0];
        float l1 = r1[0] + r1[1] + r1[2] + r1[3] + bout[1];
        float mx = fmaxf(l0, l1);
        float e0 = __expf(l0 - mx), e1 = __expf(l1 - mx);
        float s  = e0 + e1;
        out[(size_t)row * 2 + 0] = e0 / s;
        out[(size_t)row * 2 + 1] = e1 / s;
    }
}

extern "C" void kernel_launch(void* const* d_in, const int* in_sizes, int n_in,
                              void* d_out, int out_size, void* d_ws, size_t ws_size,
                              hipStream_t stream) {
    const float* x    = (const float*)d_in[0];
    const float* h    = (const float*)d_in[1];
    const float* c    = (const float*)d_in[2];
    const float* Uf   = (const float*)d_in[3];
    const float* Vf   = (const float*)d_in[4];
    const float* bfp  = (const float*)d_in[5];
    const float* Ui   = (const float*)d_in[6];
    const float* Vi   = (const float*)d_in[7];
    const float* bip  = (const float*)d_in[8];
    const float* Uo   = (const float*)d_in[9];
    const float* Vo   = (const float*)d_in[10];
    const float* bop  = (const float*)d_in[11];
    const float* Uc   = (const float*)d_in[12];
    const float* Vc   = (const float*)d_in[13];
    const float* bcp  = (const float*)d_in[14];
    const float* Wout = (const float*)d_in[15];
    const float* bout = (const float*)d_in[16];
    float* out = (float*)d_out;

    const size_t needXH = (size_t)B_ * K_ * 2;   // 64 MB
    const size_t needWt = (size_t)N_ * K_ * 2;   //  4 MB

    if (ws_size >= needXH + needWt) {
        unsigned short* XH = (unsigned short*)d_ws;
        unsigned short* Wt = (unsigned short*)((char*)d_ws + needXH);

        cvt_xh_kernel<<<(B_ * K_) / (256 * 4), 256, 0, stream>>>(x, h, XH);
        cvt_w_kernel<<<dim3(8, 8, 8), 256, 0, stream>>>(Uf, Vf, Ui, Vi, Uo, Vo, Uc, Vc, Wt);
        gemm_fused_kernel<<<dim3(16, 256), 256, 0, stream>>>(XH, Wt, c, bfp, bip, bop, bcp, out);
        logits_kernel<<<B_ / 4, 256, 0, stream>>>(out + 65536, Wout, bout, out);
    } else {
        fallback_kernel<<<B_, 256, 0, stream>>>(x, h, c, Uf, Vf, bfp, Ui, Vi, bip,
                                                Uo, Vo, bop, Uc, Vc, bcp, Wout, bout, out);
    }
}

// Round 4
// 452.778 us; speedup vs baseline: 2.3143x; 2.1949x over previous
//
#include <hip/hip_runtime.h>
#include <math.h>

#define B_   32768
#define K_   1024
#define NIT  32          // K-loop iterations (BK = 32)
#define CPT  512         // 16B chunks per operand per iter-tile: 128 rows x 4 col-chunks

typedef __bf16 bf16x8 __attribute__((ext_vector_type(8)));
typedef float  f32x4  __attribute__((ext_vector_type(4)));
typedef float  f4     __attribute__((ext_vector_type(4)));
typedef unsigned short us4 __attribute__((ext_vector_type(4)));
typedef unsigned short us8 __attribute__((ext_vector_type(8)));

__device__ __forceinline__ unsigned short f2bf(float f) {
    unsigned u = __float_as_uint(f);
    u += 0x7fffu + ((u >> 16) & 1u);   // round-to-nearest-even
    return (unsigned short)(u >> 16);
}
__device__ __forceinline__ float bf2f(unsigned short s) {
    return __uint_as_float(((unsigned)s) << 16);
}
__device__ __forceinline__ float sigm(float x) {
    return 1.f / (1.f + __expf(-x));
}
__device__ __forceinline__ float tanh_fast(float x) {
    return 1.f - 2.f / (__expf(2.f * x) + 1.f);
}
// async global->LDS, 16B per lane. LDS dest = wave-uniform base + lane*16.
__device__ __forceinline__ void gload16(const unsigned short* g, unsigned short* l) {
    __builtin_amdgcn_global_load_lds(
        (const __attribute__((address_space(1))) unsigned int*)g,
        (__attribute__((address_space(3))) unsigned int*)l, 16, 0, 0);
}

// ---------------- pack x || h -> XHt, tiled + pre-swizzled ----------------
// XHt chunk p = (mb*32 + it)*512 + r*4 + gcx holds 8 bf16 of
// XH_logical[mb*128 + r][it*32 + (gcx ^ ((r>>1)&3))*8 .. +7]  (k<512 -> x, else h)
// The gemm stage reads each iter-tile as one contiguous 8 KB block.
__global__ __launch_bounds__(256) void cvt_xh_kernel(const float* __restrict__ x,
                                                     const float* __restrict__ h,
                                                     unsigned short* __restrict__ XHt) {
    unsigned p   = blockIdx.x * 256u + threadIdx.x;   // chunk id, 4,194,304 total
    unsigned c   = p & 511u;
    unsigned T   = p >> 9;
    unsigned it  = T & 31u;
    unsigned mb  = T >> 5;
    unsigned r   = c >> 2;
    unsigned gcx = c & 3u;
    unsigned gc  = gcx ^ ((r >> 1) & 3u);
    unsigned m   = mb * 128u + r;
    unsigned k   = it * 32u + gc * 8u;
    const float* src = (k < 512u) ? (x + (size_t)m * 512u + k)
                                  : (h + (size_t)m * 512u + (k - 512u));
    f4 v0 = *(const f4*)src;
    f4 v1 = *(const f4*)(src + 4);
    us8 o;
    o[0] = f2bf(v0.x); o[1] = f2bf(v0.y); o[2] = f2bf(v0.z); o[3] = f2bf(v0.w);
    o[4] = f2bf(v1.x); o[5] = f2bf(v1.y); o[6] = f2bf(v1.z); o[7] = f2bf(v1.w);
    *(us8*)(XHt + (size_t)p * 8u) = o;
}

// ---------------- transpose-pack weights -> Wtt, tiled + pre-swizzled ----------------
// Wtt chunk p = (jb*32 + it)*512 + r*4 + gcx, r = g*32 + jj, holds
// W_logical[row = g*512 + jb*32 + jj][k = it*32 + (gcx^((jj>>1)&3))*8 .. +7]
// where k<512 -> U_g[k][j], k>=512 -> V_g[k-512][j].
__global__ __launch_bounds__(256) void cvt_w_kernel(
    const float* __restrict__ Uf, const float* __restrict__ Vf,
    const float* __restrict__ Ui, const float* __restrict__ Vi,
    const float* __restrict__ Uo, const float* __restrict__ Vo,
    const float* __restrict__ Uc, const float* __restrict__ Vc,
    unsigned short* __restrict__ Wtt) {
    __shared__ float tile[32][33];
    const float* srcs[8] = {Uf, Vf, Ui, Vi, Uo, Vo, Uc, Vc};
    const int w   = blockIdx.z;            // 0..7 : (g, isV)
    const float* src = srcs[w];
    const int g   = w >> 1;
    const int isV = w & 1;
    const int jb  = blockIdx.x;            // 0..15
    const int kw  = blockIdx.y;            // 0..15 : 32-k window within the 512
    const int j0  = jb * 32;
    const int k0  = kw * 32;
    const int it  = isV * 16 + kw;
    const int t   = threadIdx.x;
    #pragma unroll
    for (int p = 0; p < 4; ++p) {
        int kl = p * 8 + (t >> 5);
        int jj = t & 31;
        tile[kl][jj] = src[(size_t)(k0 + kl) * 512 + j0 + jj];   // coalesced over j
    }
    __syncthreads();
    if (t < 128) {
        const int jj  = t >> 2;
        const int gcx = t & 3;
        const int gc  = gcx ^ ((jj >> 1) & 3);    // (r>>1)&3 == (jj>>1)&3 since g*32 % 8 == 0
        const int r   = g * 32 + jj;
        us8 o;
        #pragma unroll
        for (int u = 0; u < 8; ++u) o[u] = f2bf(tile[gc * 8 + u][jj]);
        *(us8*)(Wtt + ((size_t)(jb * 32 + it) * 512 + r * 4 + gcx) * 8) = o;
    }
}

// ---------------- fused GEMM + LSTM gates ----------------
// 128x128 output tile (128 rows x {4 gates x 32 j}), BK=32, 4 waves, 16x16x32 MFMA.
// T3 minimum 2-phase: double-buffered LDS (2 x 16 KB), global_load_lds staging of
// tile t+1 issued BEFORE computing tile t, ONE barrier per iteration (its implicit
// vmcnt(0) drain lands after the loads had the whole compute phase in flight).
// Source layouts are tiled+pre-swizzled so LDS stays linear (m173 pattern) and
// fragment ds_read_b128 are bank-conflict-free (8-lane groups tile all 32 banks).
__global__ __launch_bounds__(256, 2) void gemm_fused_kernel(
    const unsigned short* __restrict__ XHt,
    const unsigned short* __restrict__ Wtt,
    const float* __restrict__ cell,
    const float* __restrict__ bfp, const float* __restrict__ bip,
    const float* __restrict__ bop, const float* __restrict__ bcp,
    float* __restrict__ out) {
    __shared__ __attribute__((aligned(16))) unsigned short lds[2 * 2 * CPT * 8];  // 32 KB
    const int t    = threadIdx.x;
    const int lane = t & 63;
    const int w    = t >> 6;
    const int wm   = w >> 1;
    const int wn   = w & 1;

    // XCD swizzle (bijective, 4096 % 8 == 0): each XCD gets contiguous m-strips
    // with jb fastest -> XH strip reuse in that XCD's L2 (measured -80 MB fetch).
    const unsigned lin = blockIdx.y * gridDim.x + blockIdx.x;
    const unsigned wg  = (lin & 7u) * 512u + (lin >> 3);
    const int jb = (int)(wg & 15u);
    const int mb = (int)(wg >> 4);
    const int jblk = jb * 32;
    const int m0   = mb * 128;

    f32x4 acc[4][4];
    #pragma unroll
    for (int i = 0; i < 4; ++i)
        #pragma unroll
        for (int j = 0; j < 4; ++j) { f32x4 z = {0.f, 0.f, 0.f, 0.f}; acc[i][j] = z; }

    const unsigned short* aS = XHt + (size_t)mb * (NIT * CPT * 8);
    const unsigned short* bS = Wtt + (size_t)jb * (NIT * CPT * 8);
    const int cw = w * 64;                 // wave's chunk base within a 256-chunk group

    auto stage = [&](int buf, int it) {
        const unsigned short* a = aS + (size_t)it * (CPT * 8);
        const unsigned short* b = bS + (size_t)it * (CPT * 8);
        unsigned short* lA = lds + buf * (2 * CPT * 8);
        unsigned short* lB = lA + CPT * 8;
        gload16(a + (size_t)(cw + lane) * 8,       lA + cw * 8);
        gload16(a + (size_t)(cw + lane + 256) * 8, lA + (cw + 256) * 8);
        gload16(b + (size_t)(cw + lane) * 8,       lB + cw * 8);
        gload16(b + (size_t)(cw + lane + 256) * 8, lB + (cw + 256) * 8);
    };

    const int q   = lane & 15;
    const int ccf = lane >> 4;                  // k-chunk of the fragment
    const int swz = ccf ^ ((q >> 1) & 3);       // (r>>1)&3 == (q>>1)&3 for all our rows

    auto compute = [&](int buf) {
        const unsigned short* lA = lds + buf * (2 * CPT * 8);
        const unsigned short* lB = lA + CPT * 8;
        bf16x8 af[4], bfr[4];
        #pragma unroll
        for (int mt = 0; mt < 4; ++mt)
            af[mt] = *(const bf16x8*)(lA + ((wm * 64 + mt * 16 + q) * 4 + swz) * 8);
        #pragma unroll
        for (int nt = 0; nt < 4; ++nt)
            bfr[nt] = *(const bf16x8*)(lB + ((nt * 32 + wn * 16 + q) * 4 + swz) * 8);
        #pragma unroll
        for (int mt = 0; mt < 4; ++mt)
            #pragma unroll
            for (int nt = 0; nt < 4; ++nt)
                acc[mt][nt] = __builtin_amdgcn_mfma_f32_16x16x32_bf16(af[mt], bfr[nt], acc[mt][nt], 0, 0, 0);
    };

    stage(0, 0);
    __syncthreads();                        // implicit vmcnt(0): buf0 ready
    for (int it = 0; it < NIT; it += 2) {
        if (it + 1 < NIT) stage(1, it + 1); // in flight through compute(0)
        compute(0);
        __syncthreads();                    // drains stage(1,..); readers of buf0 done
        if (it + 2 < NIT) stage(0, it + 2); // in flight through compute(1)
        compute(1);
        __syncthreads();
    }

    // ---- fused epilogue ----
    // C/D layout: col = lane&15 (-> local j), row = (lane>>4)*4 + rr; nt = gate.
    const int jc  = wn * 16 + q;               // local col in [0,32)
    const int j   = jblk + jc;                 // global hidden idx
    const float bF = bfp[j], bI = bip[j], bO = bop[j], bC = bcp[j];
    const int rlb = wm * 64 + ((lane >> 4) << 2);
    float hnv[16], cnv[16];
    #pragma unroll
    for (int mt = 0; mt < 4; ++mt) {
        #pragma unroll
        for (int rr = 0; rr < 4; ++rr) {
            const int row = m0 + rlb + mt * 16 + rr;
            const float sf = sigm(acc[mt][0][rr] + bF);
            const float si = sigm(acc[mt][1][rr] + bI);
            const float so = sigm(acc[mt][2][rr] + bO);
            const float ch = tanh_fast(acc[mt][3][rr] + bC);
            const float cold = cell[(size_t)row * 512 + j];
            const float cn = sf * cold + si * ch;
            cnv[mt * 4 + rr] = cn;
            hnv[mt * 4 + rr] = so * tanh_fast(cn);
        }
    }

    // LDS-staged full-128B-line stores (proven -60us vs scattered in round 3).
    // 128 x 36-padded f32 tile = 18.4 KB fits in the 32 KB lds.
    float* eb   = (float*)lds;
    float* hout = out + 65536;
    float* cout = out + 65536 + 16777216;
    #pragma unroll
    for (int mt = 0; mt < 4; ++mt)
        #pragma unroll
        for (int rr = 0; rr < 4; ++rr)
            eb[(rlb + mt * 16 + rr) * 36 + jc] = hnv[mt * 4 + rr];
    __syncthreads();
    #pragma unroll
    for (int i = 0; i < 4; ++i) {   // each wave-instr: 64 lanes x 16B = 8 full lines
        const int r  = i * 32 + (t >> 3);
        const int c4 = (t & 7) * 4;
        f4 v = *(const f4*)(eb + r * 36 + c4);
        *(f4*)(hout + (size_t)(m0 + r) * 512 + jblk + c4) = v;
    }
    __syncthreads();
    #pragma unroll
    for (int mt = 0; mt < 4; ++mt)
        #pragma unroll
        for (int rr = 0; rr < 4; ++rr)
            eb[(rlb + mt * 16 + rr) * 36 + jc] = cnv[mt * 4 + rr];
    __syncthreads();
    #pragma unroll
    for (int i = 0; i < 4; ++i) {
        const int r  = i * 32 + (t >> 3);
        const int c4 = (t & 7) * 4;
        f4 v = *(const f4*)(eb + r * 36 + c4);
        *(f4*)(cout + (size_t)(m0 + r) * 512 + jblk + c4) = v;
    }
}

// ---------------- logits + softmax from h_new ----------------
__global__ __launch_bounds__(256) void logits_kernel(const float* __restrict__ h,
                                                     const float* __restrict__ Wout,
                                                     const float* __restrict__ bout,
                                                     float* __restrict__ out) {
    const int t    = threadIdx.x;
    const int lane = t & 63;
    const int wv   = t >> 6;
    const int row  = blockIdx.x * 4 + wv;
    const float* hr = h + (size_t)row * 512 + lane * 8;
    f4 a = *(const f4*)(hr);
    f4 b = *(const f4*)(hr + 4);
    const float* wo = Wout + lane * 16;
    float p0 = 0.f, p1 = 0.f;
    #pragma unroll
    for (int k = 0; k < 4; ++k) { p0 += a[k] * wo[2 * k];     p1 += a[k] * wo[2 * k + 1]; }
    #pragma unroll
    for (int k = 0; k < 4; ++k) { p0 += b[k] * wo[8 + 2 * k]; p1 += b[k] * wo[8 + 2 * k + 1]; }
    #pragma unroll
    for (int off = 32; off > 0; off >>= 1) {
        p0 += __shfl_down(p0, off);
        p1 += __shfl_down(p1, off);
    }
    if (lane == 0) {
        float l0 = p0 + bout[0], l1 = p1 + bout[1];
        float mx = fmaxf(l0, l1);
        float e0 = __expf(l0 - mx), e1 = __expf(l1 - mx);
        float s  = e0 + e1;
        out[(size_t)row * 2 + 0] = e0 / s;
        out[(size_t)row * 2 + 1] = e1 / s;
    }
}

// ---------------- fallback (only if workspace is too small): naive fp32 ----------------
__global__ __launch_bounds__(256) void fallback_kernel(
    const float* __restrict__ x, const float* __restrict__ h, const float* __restrict__ cell,
    const float* __restrict__ Uf, const float* __restrict__ Vf, const float* __restrict__ bfp,
    const float* __restrict__ Ui, const float* __restrict__ Vi, const float* __restrict__ bip,
    const float* __restrict__ Uo, const float* __restrict__ Vo, const float* __restrict__ bop,
    const float* __restrict__ Uc, const float* __restrict__ Vc, const float* __restrict__ bcp,
    const float* __restrict__ Wout, const float* __restrict__ bout, float* __restrict__ out) {
    const int row = blockIdx.x;
    const int t   = threadIdx.x;
    __shared__ float xs[512], hs[512];
    xs[t]       = x[(size_t)row * 512 + t];
    xs[t + 256] = x[(size_t)row * 512 + t + 256];
    hs[t]       = h[(size_t)row * 512 + t];
    hs[t + 256] = h[(size_t)row * 512 + t + 256];
    __syncthreads();
    float p0 = 0.f, p1 = 0.f;
    for (int jj = 0; jj < 2; ++jj) {
        const int j = t + jj * 256;
        float af = bfp[j], ai = bip[j], ao = bop[j], ac = bcp[j];
        for (int k = 0; k < 512; ++k) {
            float xv = xs[k], hv = hs[k];
            af += xv * Uf[k * 512 + j] + hv * Vf[k * 512 + j];
            ai += xv * Ui[k * 512 + j] + hv * Vi[k * 512 + j];
            ao += xv * Uo[k * 512 + j] + hv * Vo[k * 512 + j];
            ac += xv * Uc[k * 512 + j] + hv * Vc[k * 512 + j];
        }
        float gf = 1.f / (1.f + __expf(-af));
        float gi = 1.f / (1.f + __expf(-ai));
        float go = 1.f / (1.f + __expf(-ao));
        float ch = tanhf(ac);
        float cold = cell[(size_t)row * 512 + j];
        float cn = gf * cold + gi * ch;
        float hn = go * tanhf(cn);
        out[65536 + (size_t)row * 512 + j]            = hn;
        out[65536 + 16777216 + (size_t)row * 512 + j] = cn;
        p0 += hn * Wout[j * 2 + 0];
        p1 += hn * Wout[j * 2 + 1];
    }
    #pragma unroll
    for (int off = 32; off > 0; off >>= 1) {
        p0 += __shfl_down(p0, off);
        p1 += __shfl_down(p1, off);
    }
    __shared__ float r0[4], r1[4];
    if ((t & 63) == 0) { r0[t >> 6] = p0; r1[t >> 6] = p1; }
    __syncthreads();
    if (t == 0) {
        float l0 = r0[0] + r0[1] + r0[2] + r0[3] + bout[0];
        float l1 = r1[0] + r1[1] + r1[2] + r1[3] + bout[1];
        float mx = fmaxf(l0, l1);
        float e0 = __expf(l0 - mx), e1 = __expf(l1 - mx);
        float s  = e0 + e1;
        out[(size_t)row * 2 + 0] = e0 / s;
        out[(size_t)row * 2 + 1] = e1 / s;
    }
}

extern "C" void kernel_launch(void* const* d_in, const int* in_sizes, int n_in,
                              void* d_out, int out_size, void* d_ws, size_t ws_size,
                              hipStream_t stream) {
    const float* x    = (const float*)d_in[0];
    const float* h    = (const float*)d_in[1];
    const float* c    = (const float*)d_in[2];
    const float* Uf   = (const float*)d_in[3];
    const float* Vf   = (const float*)d_in[4];
    const float* bfp  = (const float*)d_in[5];
    const float* Ui   = (const float*)d_in[6];
    const float* Vi   = (const float*)d_in[7];
    const float* bip  = (const float*)d_in[8];
    const float* Uo   = (const float*)d_in[9];
    const float* Vo   = (const float*)d_in[10];
    const float* bop  = (const float*)d_in[11];
    const float* Uc   = (const float*)d_in[12];
    const float* Vc   = (const float*)d_in[13];
    const float* bcp  = (const float*)d_in[14];
    const float* Wout = (const float*)d_in[15];
    const float* bout = (const float*)d_in[16];
    float* out = (float*)d_out;

    const size_t needXH = (size_t)B_ * K_ * 2;   // 64 MB
    const size_t needWt = (size_t)2048 * K_ * 2; //  4 MB

    if (ws_size >= needXH + needWt) {
        unsigned short* XHt = (unsigned short*)d_ws;
        unsigned short* Wtt = (unsigned short*)((char*)d_ws + needXH);

        cvt_xh_kernel<<<(B_ * K_) / (256 * 8), 256, 0, stream>>>(x, h, XHt);
        cvt_w_kernel<<<dim3(16, 16, 8), 256, 0, stream>>>(Uf, Vf, Ui, Vi, Uo, Vo, Uc, Vc, Wtt);
        gemm_fused_kernel<<<dim3(16, 256), 256, 0, stream>>>(XHt, Wtt, c, bfp, bip, bop, bcp, out);
        logits_kernel<<<B_ / 4, 256, 0, stream>>>(out + 65536, Wout, bout, out);
    } else {
        fallback_kernel<<<B_, 256, 0, stream>>>(x, h, c, Uf, Vf, bfp, Ui, Vi, bip,
                                                Uo, Vo, bop, Uc, Vc, bcp, Wout, bout, out);
    }
}